// Round 4
// baseline (103.577 us; speedup 1.0000x reference)
//
#include <hip/hip_runtime.h>
#include <hip/hip_cooperative_groups.h>
#include <math.h>

namespace cg = cooperative_groups;

// Problem constants: B=16, N=128, h=256, goal_dim=64, obs_dim=128, local=64, skills=16

typedef float f32x4 __attribute__((ext_vector_type(4)));
typedef short s16x8 __attribute__((ext_vector_type(8)));

// ---- workspace layout (float offsets) ----
#define WOBF_OFF  0        // bf16 [256][256] (row-major, = original Wo layout)
#define QBF_OFF   32768    // bf16 [2048][256] row-major
#define KBF_OFF   294912   // bf16 [2048][256] row-major
#define VTBF_OFF  557056   // bf16 [16][256][128]  (V transposed per batch)
// end 819200 floats = 3.3 MB

// ---- output layout (float offsets, tuple return order) ----
#define LOGIT_OFF 0        // [16][128][16]
#define MASK_OFF  32768    // [16][128][128]
#define ATTN_OFF  294912   // [16][128][128]
#define OUT_OFF   557056   // [16][128][256]

static __device__ __forceinline__ unsigned short f2bf(float x) {
  unsigned int u = __float_as_uint(x);
  u = (u + 0x7fffu + ((u >> 16) & 1u)) >> 16;   // RNE
  return (unsigned short)u;
}

// 256 blocks x 512 threads, cooperative. Phase A: projections (8 rows/block).
// grid.sync(). Phase B: attention tile (b = bid&15, n0 = (bid>>4)*8).
__global__ __launch_bounds__(512) void fused_k(
    const float* __restrict__ goals, const float* __restrict__ agents,
    const float* __restrict__ agents_local,
    const float* __restrict__ u1, const float* __restrict__ u2,
    const float* __restrict__ Wq, const float* __restrict__ bq,
    const float* __restrict__ Wk, const float* __restrict__ bk,
    const float* __restrict__ Wv, const float* __restrict__ bv,
    const float* __restrict__ Wo, const float* __restrict__ bo,
    const float* __restrict__ Wsm, const float* __restrict__ bs,
    float* __restrict__ ws, float* __restrict__ out) {
  unsigned short* qbf  = (unsigned short*)(ws + QBF_OFF);
  unsigned short* kbf  = (unsigned short*)(ws + KBF_OFF);
  unsigned short* vtbf = (unsigned short*)(ws + VTBF_OFF);
  unsigned short* wobf = (unsigned short*)(ws + WOBF_OFF);

  int t = threadIdx.x;
  int bid = blockIdx.x;

  __shared__ __align__(16) float xg[8][64];              // phase A: goal rows
  __shared__ __align__(16) float xa[8][128];             // phase A: agent rows
  __shared__ __align__(16) float S[16 * 140];            // logits f32
  __shared__ __align__(16) unsigned short Wb[16 * 136];  // attn*mask bf16 (A of PV)
  __shared__ __align__(16) unsigned short Ib[16 * 264];  // info bf16 (A of out-proj)
  __shared__ __align__(16) float outb[8 * 260];          // out rows f32 (skill input)
  __shared__ float redmax[8][2], redsum[8][2];

  // ================= Phase A: projections =================
  {
    int r0 = bid * 8;          // global row block (2048 rows total)
    int bb = r0 >> 7;          // batch
    // load 8 goal rows (512 f32) + 8 agent rows (1024 f32)
    xg[t >> 6][t & 63] = goals[(size_t)r0 * 64 + t];
    xa[t >> 7][t & 127] = agents[(size_t)r0 * 128 + t];
    {
      int i = t + 512;
      xa[i >> 7][i & 127] = agents[(size_t)r0 * 128 + i];
    }
    __syncthreads();

    int o = t & 255, rseg = t >> 8;   // 4 rows per thread
    // ---- Q: dot-64 ----
    {
      const float4* wq4 = (const float4*)(Wq + (size_t)o * 64);
      float acc[4] = {0.f, 0.f, 0.f, 0.f};
      for (int d = 0; d < 64; d += 4) {
        float4 w = wq4[d >> 2];
#pragma unroll
        for (int r = 0; r < 4; r++) {
          float4 x = *(const float4*)&xg[rseg * 4 + r][d];
          acc[r] = fmaf(w.x, x.x, acc[r]);
          acc[r] = fmaf(w.y, x.y, acc[r]);
          acc[r] = fmaf(w.z, x.z, acc[r]);
          acc[r] = fmaf(w.w, x.w, acc[r]);
        }
      }
      float bqv = bq[o];
#pragma unroll
      for (int r = 0; r < 4; r++)
        qbf[(size_t)(r0 + rseg * 4 + r) * 256 + o] = f2bf(acc[r] + bqv);
    }
    // ---- K and V: dot-128 ----
    {
      const float4* wk4 = (const float4*)(Wk + (size_t)o * 128);
      const float4* wv4 = (const float4*)(Wv + (size_t)o * 128);
      float accK[4] = {0.f, 0.f, 0.f, 0.f};
      float accV[4] = {0.f, 0.f, 0.f, 0.f};
      for (int d = 0; d < 128; d += 4) {
        float4 wk = wk4[d >> 2];
        float4 wv = wv4[d >> 2];
#pragma unroll
        for (int r = 0; r < 4; r++) {
          float4 x = *(const float4*)&xa[rseg * 4 + r][d];
          accK[r] = fmaf(wk.x, x.x, accK[r]); accK[r] = fmaf(wk.y, x.y, accK[r]);
          accK[r] = fmaf(wk.z, x.z, accK[r]); accK[r] = fmaf(wk.w, x.w, accK[r]);
          accV[r] = fmaf(wv.x, x.x, accV[r]); accV[r] = fmaf(wv.y, x.y, accV[r]);
          accV[r] = fmaf(wv.z, x.z, accV[r]); accV[r] = fmaf(wv.w, x.w, accV[r]);
        }
      }
      float bkv = bk[o], bvv = bv[o];
      int m0 = r0 & 127;
#pragma unroll
      for (int r = 0; r < 4; r++) {
        kbf[(size_t)(r0 + rseg * 4 + r) * 256 + o] = f2bf(accK[r] + bkv);
        vtbf[(size_t)(bb * 256 + o) * 128 + m0 + rseg * 4 + r] = f2bf(accV[r] + bvv);
      }
    }
    // ---- Wo -> bf16, 256 elems per block ----
    if (t < 256) {
      int j = bid * 256 + t;
      wobf[j] = f2bf(Wo[j]);
    }
  }

  cg::this_grid().sync();

  // ================= Phase B: attention =================
  const unsigned short* Qbf  = qbf;
  const unsigned short* Kbf  = kbf;
  const unsigned short* VTbf = vtbf;
  const unsigned short* Wobf = wobf;
  float* o_logit = out + LOGIT_OFF;
  float* o_mask  = out + MASK_OFF;
  float* o_attn  = out + ATTN_OFF;
  float* o_out   = out + OUT_OFF;

  int b  = bid & 15;
  int n0 = (bid >> 4) << 3;
  int rtile = n0 & 0x70;      // 16-row MFMA window
  int soff  = n0 & 8;         // our half within the window
  int w = t >> 6, l = t & 63, lr = l & 15, lc = l >> 4;

  // ---- phase L: logits via MFMA.  D[row][m] = sum_h Q[row][h] K[m][h] ----
  {
    const s16x8* ap = (const s16x8*)(Qbf + (size_t)(b * 128 + rtile + lr) * 256);
    const s16x8* bp = (const s16x8*)(Kbf + (size_t)(b * 128 + 16 * w + lr) * 256);
    f32x4 acc = {0.f, 0.f, 0.f, 0.f};
#pragma unroll
    for (int kk = 0; kk < 8; kk++)
      acc = __builtin_amdgcn_mfma_f32_16x16x32_bf16(ap[kk * 4 + lc], bp[kk * 4 + lc], acc, 0, 0, 0);
#pragma unroll
    for (int q = 0; q < 4; q++) S[(4 * lc + q) * 140 + 16 * w + lr] = acc[q] * 0.0625f;
    // zero the other-half rows of Wb (A rows we don't own -> zero rows in PV)
    unsigned int* wz = (unsigned int*)(Wb + (soff ^ 8) * 136);
    for (int i = t; i < 544; i += 512) wz[i] = 0u;
  }
  __syncthreads();

  // ---- phase S: gumbel-sigmoid mask + scores + softmax (2 rows/thread, f32) ----
  {
    int m = t & 127, rg = t >> 7, half = (t >> 6) & 1;
    int rl0 = 2 * rg;
    float sc[2], mk[2], ev[2];
#pragma unroll
    for (int i = 0; i < 2; i++) {
      int rloc = rl0 + i;
      float lg = S[(soff + rloc) * 140 + m];
      int row = b * 128 + n0 + rloc;
      float uu1 = u1[row * 128 + m];
      float uu2 = u2[row * 128 + m];
      float g1 = -__logf(-__logf(uu1 + 1e-20f) + 1e-20f);
      float g2 = -__logf(-__logf(uu2 + 1e-20f) + 1e-20f);
      float z = lg + g1 - g2;                       // TAU = 1
      float mkv = 1.0f / (1.0f + __expf(-z));
      mk[i] = mkv;
      o_mask[row * 128 + m] = mkv;
      sc[i] = lg + __logf(mkv + 1e-8f);
    }
    float v0 = sc[0], v1 = sc[1];
#pragma unroll
    for (int off = 32; off >= 1; off >>= 1) {
      v0 = fmaxf(v0, __shfl_xor(v0, off));
      v1 = fmaxf(v1, __shfl_xor(v1, off));
    }
    if ((t & 63) == 0) { redmax[rl0][half] = v0; redmax[rl0 + 1][half] = v1; }
    __syncthreads();
#pragma unroll
    for (int i = 0; i < 2; i++) {
      float rmax = fmaxf(redmax[rl0 + i][0], redmax[rl0 + i][1]);
      ev[i] = __expf(sc[i] - rmax);
    }
    float s0 = ev[0], s1 = ev[1];
#pragma unroll
    for (int off = 32; off >= 1; off >>= 1) {
      s0 += __shfl_xor(s0, off);
      s1 += __shfl_xor(s1, off);
    }
    if ((t & 63) == 0) { redsum[rl0][half] = s0; redsum[rl0 + 1][half] = s1; }
    __syncthreads();
#pragma unroll
    for (int i = 0; i < 2; i++) {
      int rloc = rl0 + i;
      float rsum = redsum[rloc][0] + redsum[rloc][1];
      float attn = ev[i] / rsum;
      int row = b * 128 + n0 + rloc;
      o_attn[row * 128 + m] = attn;
      Wb[(soff + rloc) * 136 + m] = f2bf(attn * mk[i]);
    }
  }
  __syncthreads();

  // ---- phase PV: info[row][h] = sum_m W[row][m] V[m][h] ----
  {
#pragma unroll
    for (int hs = 0; hs < 2; hs++) {
      int h0 = (w + 8 * hs) * 16;
      f32x4 acc = {0.f, 0.f, 0.f, 0.f};
#pragma unroll
      for (int kk = 0; kk < 4; kk++) {
        s16x8 a = *(const s16x8*)(Wb + lr * 136 + kk * 32 + lc * 8);
        s16x8 bf = *(const s16x8*)(VTbf + (size_t)(b * 256 + h0 + lr) * 128 + kk * 32 + lc * 8);
        acc = __builtin_amdgcn_mfma_f32_16x16x32_bf16(a, bf, acc, 0, 0, 0);
      }
#pragma unroll
      for (int q = 0; q < 4; q++) Ib[(4 * lc + q) * 264 + h0 + lr] = f2bf(acc[q]);
    }
  }
  __syncthreads();

  // ---- phase O: out[row][g] = sum_h info[row][h] Wo[g][h] + bo[g] ----
  {
#pragma unroll
    for (int gs = 0; gs < 2; gs++) {
      int g0 = (w + 8 * gs) * 16;
      f32x4 acc = {0.f, 0.f, 0.f, 0.f};
#pragma unroll
      for (int kk = 0; kk < 8; kk++) {
        s16x8 a = *(const s16x8*)(Ib + lr * 264 + kk * 32 + lc * 8);
        s16x8 bf = *(const s16x8*)(Wobf + (size_t)(g0 + lr) * 256 + kk * 32 + lc * 8);
        acc = __builtin_amdgcn_mfma_f32_16x16x32_bf16(a, bf, acc, 0, 0, 0);
      }
      float bov = bo[g0 + lr];
      if ((lc >> 1) == (soff >> 3)) {                 // rows we own
#pragma unroll
        for (int q = 0; q < 4; q++) {
          int rloc = (4 * lc + q) & 7;
          float val = acc[q] + bov;
          o_out[(size_t)(b * 128 + n0 + rloc) * 256 + g0 + lr] = val;
          outb[rloc * 260 + g0 + lr] = val;
        }
      }
    }
  }
  __syncthreads();

  // ---- phase K: skill logits, f32. t = (rloc<<6) | (s<<2) | p ----
  {
    int rloc = t >> 6, s = (t >> 2) & 15, p = t & 3;
    int row = b * 128 + n0 + rloc;
    const float4* Ws4 = (const float4*)(Wsm + s * 384);
    const float4* lp4 = (const float4*)(agents_local + (size_t)row * 64);
    const float4* gp4 = (const float4*)(goals + (size_t)row * 64);
    float acc = 0.f;
#pragma unroll
    for (int i = 0; i < 24; i++) {
      int cc = p * 96 + i * 4;
      float4 c4;
      if (cc < 64)       c4 = lp4[cc >> 2];
      else if (cc < 128) c4 = gp4[(cc - 64) >> 2];
      else               c4 = *(const float4*)&outb[rloc * 260 + (cc - 128)];
      float4 w4 = Ws4[cc >> 2];
      acc = fmaf(w4.x, c4.x, fmaf(w4.y, c4.y, fmaf(w4.z, c4.z, fmaf(w4.w, c4.w, acc))));
    }
    acc += __shfl_xor(acc, 1);
    acc += __shfl_xor(acc, 2);
    if (p == 0) o_logit[row * 16 + s] = acc + bs[s];
  }
}

extern "C" void kernel_launch(void* const* d_in, const int* in_sizes, int n_in,
                              void* d_out, int out_size, void* d_ws, size_t ws_size,
                              hipStream_t stream) {
  const float* goals        = (const float*)d_in[0];
  const float* agents       = (const float*)d_in[1];
  const float* agents_local = (const float*)d_in[2];
  const float* u1           = (const float*)d_in[3];
  const float* u2           = (const float*)d_in[4];
  const float* Wq = (const float*)d_in[5];
  const float* bq = (const float*)d_in[6];
  const float* Wk = (const float*)d_in[7];
  const float* bk = (const float*)d_in[8];
  const float* Wv = (const float*)d_in[9];
  const float* bv = (const float*)d_in[10];
  const float* Wo = (const float*)d_in[11];
  const float* bo = (const float*)d_in[12];
  const float* Wsm = (const float*)d_in[13];
  const float* bs  = (const float*)d_in[14];
  float* out = (float*)d_out;
  float* ws  = (float*)d_ws;

  void* args[] = {
    (void*)&goals, (void*)&agents, (void*)&agents_local, (void*)&u1, (void*)&u2,
    (void*)&Wq, (void*)&bq, (void*)&Wk, (void*)&bk, (void*)&Wv, (void*)&bv,
    (void*)&Wo, (void*)&bo, (void*)&Wsm, (void*)&bs, (void*)&ws, (void*)&out
  };
  hipLaunchCooperativeKernel((void*)fused_k, dim3(256), dim3(512), args, 0, stream);
}

// Round 5
// 50.023 us; speedup vs baseline: 2.0706x; 2.0706x over previous
//
#include <hip/hip_runtime.h>
#include <math.h>

// Problem constants: B=16, N=128, h=256, goal_dim=64, obs_dim=128, local=64, skills=16

typedef float f32x4 __attribute__((ext_vector_type(4)));
typedef short s16x8 __attribute__((ext_vector_type(8)));

// ---- workspace layout (float offsets) ----
#define WOBF_OFF  0        // bf16 [256][256] (row-major, = original Wo layout)
#define QBF_OFF   32768    // bf16 [2048][256] row-major
#define KBF_OFF   294912   // bf16 [2048][256] row-major
#define VTBF_OFF  557056   // bf16 [16][256][128]  (V transposed per batch)

// ---- output layout (float offsets, tuple return order) ----
#define LOGIT_OFF 0        // [16][128][16]
#define MASK_OFF  32768    // [16][128][128]
#define ATTN_OFF  294912   // [16][128][128]
#define OUT_OFF   557056   // [16][128][256]

static __device__ __forceinline__ unsigned short f2bf(float x) {
  unsigned int u = __float_as_uint(x);
  u = (u + 0x7fffu + ((u >> 16) & 1u)) >> 16;   // RNE
  return (unsigned short)u;
}

// 256 blocks x 512 threads: projections, 8 rows/block, reading ORIGINAL weight
// layouts (per-thread-contiguous rows). Also converts Wo -> bf16.
__global__ __launch_bounds__(512) void proj_k(
    const float* __restrict__ goals, const float* __restrict__ agents,
    const float* __restrict__ Wq, const float* __restrict__ bq,
    const float* __restrict__ Wk, const float* __restrict__ bk,
    const float* __restrict__ Wv, const float* __restrict__ bv,
    const float* __restrict__ Wo, float* __restrict__ ws) {
  unsigned short* qbf  = (unsigned short*)(ws + QBF_OFF);
  unsigned short* kbf  = (unsigned short*)(ws + KBF_OFF);
  unsigned short* vtbf = (unsigned short*)(ws + VTBF_OFF);
  unsigned short* wobf = (unsigned short*)(ws + WOBF_OFF);

  int t = threadIdx.x;
  int bid = blockIdx.x;

  __shared__ __align__(16) float xg[8][64];
  __shared__ __align__(16) float xa[8][128];

  int r0 = bid * 8;          // global row block (2048 rows total)
  int bb = r0 >> 7;          // batch
  xg[t >> 6][t & 63] = goals[(size_t)r0 * 64 + t];
  xa[t >> 7][t & 127] = agents[(size_t)r0 * 128 + t];
  {
    int i = t + 512;
    xa[i >> 7][i & 127] = agents[(size_t)r0 * 128 + i];
  }
  __syncthreads();

  int o = t & 255, rseg = t >> 8;   // 4 rows per thread
  // ---- Q: dot-64 ----
  {
    const float4* wq4 = (const float4*)(Wq + (size_t)o * 64);
    float acc[4] = {0.f, 0.f, 0.f, 0.f};
    for (int d = 0; d < 64; d += 4) {
      float4 w = wq4[d >> 2];
#pragma unroll
      for (int r = 0; r < 4; r++) {
        float4 x = *(const float4*)&xg[rseg * 4 + r][d];
        acc[r] = fmaf(w.x, x.x, acc[r]);
        acc[r] = fmaf(w.y, x.y, acc[r]);
        acc[r] = fmaf(w.z, x.z, acc[r]);
        acc[r] = fmaf(w.w, x.w, acc[r]);
      }
    }
    float bqv = bq[o];
#pragma unroll
    for (int r = 0; r < 4; r++)
      qbf[(size_t)(r0 + rseg * 4 + r) * 256 + o] = f2bf(acc[r] + bqv);
  }
  // ---- K and V: dot-128 ----
  {
    const float4* wk4 = (const float4*)(Wk + (size_t)o * 128);
    const float4* wv4 = (const float4*)(Wv + (size_t)o * 128);
    float accK[4] = {0.f, 0.f, 0.f, 0.f};
    float accV[4] = {0.f, 0.f, 0.f, 0.f};
    for (int d = 0; d < 128; d += 4) {
      float4 wk = wk4[d >> 2];
      float4 wv = wv4[d >> 2];
#pragma unroll
      for (int r = 0; r < 4; r++) {
        float4 x = *(const float4*)&xa[rseg * 4 + r][d];
        accK[r] = fmaf(wk.x, x.x, accK[r]); accK[r] = fmaf(wk.y, x.y, accK[r]);
        accK[r] = fmaf(wk.z, x.z, accK[r]); accK[r] = fmaf(wk.w, x.w, accK[r]);
        accV[r] = fmaf(wv.x, x.x, accV[r]); accV[r] = fmaf(wv.y, x.y, accV[r]);
        accV[r] = fmaf(wv.z, x.z, accV[r]); accV[r] = fmaf(wv.w, x.w, accV[r]);
      }
    }
    float bkv = bk[o], bvv = bv[o];
    int m0 = r0 & 127;
#pragma unroll
    for (int r = 0; r < 4; r++) {
      kbf[(size_t)(r0 + rseg * 4 + r) * 256 + o] = f2bf(accK[r] + bkv);
      vtbf[(size_t)(bb * 256 + o) * 128 + m0 + rseg * 4 + r] = f2bf(accV[r] + bvv);
    }
  }
  // ---- Wo -> bf16, 256 elems per block ----
  if (t < 256) {
    int j = bid * 256 + t;
    wobf[j] = f2bf(Wo[j]);
  }
}

// 256 blocks x 1024 threads (16 waves, 50% occ ceiling). One (b, 8-row) tile
// per block; every phase split across all 16 waves; u1/u2 prefetched.
__global__ __launch_bounds__(1024, 4) void attn_k(
    const float* __restrict__ goals, const float* __restrict__ agents_local,
    const float* __restrict__ u1, const float* __restrict__ u2,
    const float* __restrict__ bo, const float* __restrict__ Wsm,
    const float* __restrict__ bs, const float* __restrict__ ws,
    float* __restrict__ out) {
  const unsigned short* Qbf  = (const unsigned short*)(ws + QBF_OFF);
  const unsigned short* Kbf  = (const unsigned short*)(ws + KBF_OFF);
  const unsigned short* VTbf = (const unsigned short*)(ws + VTBF_OFF);
  const unsigned short* Wobf = (const unsigned short*)(ws + WOBF_OFF);
  float* o_logit = out + LOGIT_OFF;
  float* o_mask  = out + MASK_OFF;
  float* o_attn  = out + ATTN_OFF;
  float* o_out   = out + OUT_OFF;

  int bid = blockIdx.x;
  int b  = bid & 15;
  int n0 = (bid >> 4) << 3;
  int rtile = n0 & 0x70;      // 16-row MFMA window
  int soff  = n0 & 8;         // our half within the window
  int t = threadIdx.x;
  int w = t >> 6, l = t & 63, lr = l & 15, lc = l >> 4;

  __shared__ float Sp[2][16][132];                       // logits k-half partials
  __shared__ __align__(16) unsigned short Wb[16 * 136];  // attn*mask bf16 (A of PV)
  __shared__ __align__(16) unsigned short Ib[16 * 264];  // info bf16 (A of out-proj)
  __shared__ __align__(16) float outb[8 * 260];          // out rows f32 (skill input)
  __shared__ float redmax[8][2], redsum[8][2];

  // ---- prefetch (hide HBM latency under phase L) ----
  int pm = t & 127, prl = t >> 7;
  int prow = b * 128 + n0 + prl;
  float uu1 = u1[(size_t)prow * 128 + pm];
  float uu2 = u2[(size_t)prow * 128 + pm];
  float bov = bo[w * 16 + lr];

  // ---- phase L: logits MFMA, k-split. wave w: m-tile=w&7, k-half=w>>3 ----
  {
    int mt = w & 7, kh = w >> 3;
    const s16x8* ap = (const s16x8*)(Qbf + (size_t)(b * 128 + rtile + lr) * 256 + kh * 128);
    const s16x8* bp = (const s16x8*)(Kbf + (size_t)(b * 128 + mt * 16 + lr) * 256 + kh * 128);
    f32x4 acc = {0.f, 0.f, 0.f, 0.f};
#pragma unroll
    for (int kk = 0; kk < 4; kk++)
      acc = __builtin_amdgcn_mfma_f32_16x16x32_bf16(ap[kk * 4 + lc], bp[kk * 4 + lc], acc, 0, 0, 0);
#pragma unroll
    for (int q = 0; q < 4; q++) Sp[kh][4 * lc + q][mt * 16 + lr] = acc[q];
    // zero the other-half rows of Wb (8 rows x 136 bf16 = 544 u32)
    if (t < 544) ((unsigned int*)(Wb + (soff ^ 8) * 136))[t] = 0u;
  }
  __syncthreads();

  // ---- phase S: mask + scores + softmax. 1 (row,m) per thread ----
  {
    int half = (t >> 6) & 1;
    float lg = (Sp[0][soff + prl][pm] + Sp[1][soff + prl][pm]) * 0.0625f;
    float g1 = -__logf(-__logf(uu1 + 1e-20f) + 1e-20f);
    float g2 = -__logf(-__logf(uu2 + 1e-20f) + 1e-20f);
    float z = lg + g1 - g2;                       // TAU = 1
    float mkv = 1.0f / (1.0f + __expf(-z));
    o_mask[(size_t)prow * 128 + pm] = mkv;
    float sc = lg + __logf(mkv + 1e-8f);
    float v = sc;
#pragma unroll
    for (int off = 32; off >= 1; off >>= 1) v = fmaxf(v, __shfl_xor(v, off));
    if (l == 0) redmax[prl][half] = v;
    __syncthreads();
    float rmax = fmaxf(redmax[prl][0], redmax[prl][1]);
    float e = __expf(sc - rmax);
    float s = e;
#pragma unroll
    for (int off = 32; off >= 1; off >>= 1) s += __shfl_xor(s, off);
    if (l == 0) redsum[prl][half] = s;
    __syncthreads();
    float rsum = redsum[prl][0] + redsum[prl][1];
    float attn = e / rsum;
    o_attn[(size_t)prow * 128 + pm] = attn;
    Wb[(soff + prl) * 136 + pm] = f2bf(attn * mkv);
  }
  __syncthreads();

  // ---- phase PV: info = W x V. wave w -> h-tile h0 = w*16, k=128 ----
  {
    int h0 = w * 16;
    f32x4 acc = {0.f, 0.f, 0.f, 0.f};
#pragma unroll
    for (int kk = 0; kk < 4; kk++) {
      s16x8 a = *(const s16x8*)(Wb + lr * 136 + kk * 32 + lc * 8);
      s16x8 bfr = *(const s16x8*)(VTbf + (size_t)(b * 256 + h0 + lr) * 128 + kk * 32 + lc * 8);
      acc = __builtin_amdgcn_mfma_f32_16x16x32_bf16(a, bfr, acc, 0, 0, 0);
    }
#pragma unroll
    for (int q = 0; q < 4; q++) Ib[(4 * lc + q) * 264 + h0 + lr] = f2bf(acc[q]);
  }
  __syncthreads();

  // ---- phase O: out = info x Wo^T. wave w -> g-tile g0 = w*16, k=256 ----
  {
    int g0 = w * 16;
    f32x4 acc = {0.f, 0.f, 0.f, 0.f};
#pragma unroll
    for (int kk = 0; kk < 8; kk++) {
      s16x8 a = *(const s16x8*)(Ib + lr * 264 + kk * 32 + lc * 8);
      s16x8 bfr = *(const s16x8*)(Wobf + (size_t)(g0 + lr) * 256 + kk * 32 + lc * 8);
      acc = __builtin_amdgcn_mfma_f32_16x16x32_bf16(a, bfr, acc, 0, 0, 0);
    }
    if ((lc >> 1) == (soff >> 3)) {                 // rows we own
#pragma unroll
      for (int q = 0; q < 4; q++) {
        int rloc = (4 * lc + q) & 7;
        float val = acc[q] + bov;
        o_out[(size_t)(b * 128 + n0 + rloc) * 256 + g0 + lr] = val;
        outb[rloc * 260 + g0 + lr] = val;
      }
    }
  }
  __syncthreads();

  // ---- phase K: skill logits. t = (rloc<<7)|(s<<3)|p, 8-way split-K of 384 ----
  {
    int outi = t >> 3, p = t & 7;
    int rloc = outi >> 4, s = outi & 15;
    int row = b * 128 + n0 + rloc;
    const float4* Ws4 = (const float4*)(Wsm + s * 384);
    const float4* lp4 = (const float4*)(agents_local + (size_t)row * 64);
    const float4* gp4 = (const float4*)(goals + (size_t)row * 64);
    float acc = 0.f;
#pragma unroll
    for (int i = 0; i < 12; i++) {
      int cc = p * 48 + i * 4;
      float4 c4;
      if (cc < 64)       c4 = lp4[cc >> 2];
      else if (cc < 128) c4 = gp4[(cc - 64) >> 2];
      else               c4 = *(const float4*)&outb[rloc * 260 + (cc - 128)];
      float4 w4 = Ws4[cc >> 2];
      acc = fmaf(w4.x, c4.x, fmaf(w4.y, c4.y, fmaf(w4.z, c4.z, fmaf(w4.w, c4.w, acc))));
    }
    acc += __shfl_xor(acc, 1);
    acc += __shfl_xor(acc, 2);
    acc += __shfl_xor(acc, 4);
    if (p == 0) o_logit[row * 16 + s] = acc + bs[s];
  }
}

extern "C" void kernel_launch(void* const* d_in, const int* in_sizes, int n_in,
                              void* d_out, int out_size, void* d_ws, size_t ws_size,
                              hipStream_t stream) {
  const float* goals        = (const float*)d_in[0];
  const float* agents       = (const float*)d_in[1];
  const float* agents_local = (const float*)d_in[2];
  const float* u1           = (const float*)d_in[3];
  const float* u2           = (const float*)d_in[4];
  const float* Wq = (const float*)d_in[5];
  const float* bq = (const float*)d_in[6];
  const float* Wk = (const float*)d_in[7];
  const float* bk = (const float*)d_in[8];
  const float* Wv = (const float*)d_in[9];
  const float* bv = (const float*)d_in[10];
  const float* Wo = (const float*)d_in[11];
  const float* bo = (const float*)d_in[12];
  const float* Wsm = (const float*)d_in[13];
  const float* bs  = (const float*)d_in[14];
  float* out = (float*)d_out;
  float* ws  = (float*)d_ws;

  proj_k<<<256, 512, 0, stream>>>(goals, agents, Wq, bq, Wk, bk, Wv, bv, Wo, ws);
  attn_k<<<256, 1024, 0, stream>>>(goals, agents_local, u1, u2, bo, Wsm, bs, ws, out);
}

// Round 6
// 41.850 us; speedup vs baseline: 2.4750x; 1.1953x over previous
//
#include <hip/hip_runtime.h>
#include <math.h>

// Problem constants: B=16, N=128, h=256, goal_dim=64, obs_dim=128, local=64, skills=16

typedef float f32x4 __attribute__((ext_vector_type(4)));
typedef short s16x8 __attribute__((ext_vector_type(8)));

// ---- workspace layout (float offsets) ----
#define WOBF_OFF  0        // bf16 [256][256] (row-major, = original Wo layout)
#define QBF_OFF   32768    // bf16 [2048][256] row-major
#define KBF_OFF   294912   // bf16 [2048][256] row-major
#define VTBF_OFF  557056   // bf16 [16][256][128]  (V transposed per batch)

// ---- output layout (float offsets, tuple return order) ----
#define LOGIT_OFF 0        // [16][128][16]
#define MASK_OFF  32768    // [16][128][128]
#define ATTN_OFF  294912   // [16][128][128]
#define OUT_OFF   557056   // [16][128][256]

static __device__ __forceinline__ unsigned short f2bf(float x) {
  unsigned int u = __float_as_uint(x);
  u = (u + 0x7fffu + ((u >> 16) & 1u)) >> 16;   // RNE
  return (unsigned short)u;
}
static __device__ __forceinline__ float bf2f(unsigned short h) {
  return __uint_as_float(((unsigned int)h) << 16);
}

// split 8 consecutive f32 (16B-aligned) into hi/lo bf16 MFMA fragments
static __device__ __forceinline__ void split8(const float* __restrict__ p,
                                              s16x8* hi, s16x8* lo) {
  float4 x0 = *(const float4*)p;
  float4 x1 = *(const float4*)(p + 4);
  float xs[8] = {x0.x, x0.y, x0.z, x0.w, x1.x, x1.y, x1.z, x1.w};
#pragma unroll
  for (int j = 0; j < 8; j++) {
    unsigned short h = f2bf(xs[j]);
    (*hi)[j] = (short)h;
    (*lo)[j] = (short)f2bf(xs[j] - bf2f(h));
  }
}

// 256 blocks x 512 threads. block = (16-row window = bid>>1, col-half = bid&1).
// MFMA projections with hi/lo 3-term compensation (~f32 accuracy).
// Wave w handles output cols [colbase + w*16, +16).
__global__ __launch_bounds__(512) void proj_k(
    const float* __restrict__ goals, const float* __restrict__ agents,
    const float* __restrict__ Wq, const float* __restrict__ bq,
    const float* __restrict__ Wk, const float* __restrict__ bk,
    const float* __restrict__ Wv, const float* __restrict__ bv,
    const float* __restrict__ Wo, float* __restrict__ ws) {
  unsigned short* qbf  = (unsigned short*)(ws + QBF_OFF);
  unsigned short* kbf  = (unsigned short*)(ws + KBF_OFF);
  unsigned short* vtbf = (unsigned short*)(ws + VTBF_OFF);
  unsigned short* wobf = (unsigned short*)(ws + WOBF_OFF);

  __shared__ __align__(16) float xg[16 * 68];    // goal rows, stride 68
  __shared__ __align__(16) float xa[16 * 132];   // agent rows, stride 132

  int t = threadIdx.x;
  int bid = blockIdx.x;
  int r0 = (bid >> 1) * 16;
  int colbase = (bid & 1) * 128;
  int bb = r0 >> 7;

  for (int i = t; i < 1024; i += 512) xg[(i >> 6) * 68 + (i & 63)] = goals[(size_t)r0 * 64 + i];
  for (int i = t; i < 2048; i += 512) xa[(i >> 7) * 132 + (i & 127)] = agents[(size_t)r0 * 128 + i];
  if (t < 256) {                                  // Wo -> bf16 (256/block x 256 blocks)
    int j = bid * 256 + t;
    wobf[j] = f2bf(Wo[j]);
  }
  __syncthreads();

  int w = t >> 6, l = t & 63, lr = l & 15, lc = l >> 4;
  int oc = colbase + w * 16 + lr;                 // output col = weight row

  // ---- Q: k=64 (2 ksteps x 3 MFMA) ----
  {
    f32x4 acc = {0.f, 0.f, 0.f, 0.f};
#pragma unroll
    for (int kk = 0; kk < 2; kk++) {
      s16x8 ahi, alo, bhi, blo;
      split8(&xg[lr * 68 + kk * 32 + lc * 8], &ahi, &alo);
      split8(&Wq[(size_t)oc * 64 + kk * 32 + lc * 8], &bhi, &blo);
      acc = __builtin_amdgcn_mfma_f32_16x16x32_bf16(ahi, bhi, acc, 0, 0, 0);
      acc = __builtin_amdgcn_mfma_f32_16x16x32_bf16(alo, bhi, acc, 0, 0, 0);
      acc = __builtin_amdgcn_mfma_f32_16x16x32_bf16(ahi, blo, acc, 0, 0, 0);
    }
    float bqv = bq[oc];
#pragma unroll
    for (int q = 0; q < 4; q++)
      qbf[(size_t)(r0 + 4 * lc + q) * 256 + oc] = f2bf(acc[q] + bqv);
  }
  // ---- K: k=128 (4 ksteps x 3 MFMA) ----
  {
    f32x4 acc = {0.f, 0.f, 0.f, 0.f};
#pragma unroll
    for (int kk = 0; kk < 4; kk++) {
      s16x8 ahi, alo, bhi, blo;
      split8(&xa[lr * 132 + kk * 32 + lc * 8], &ahi, &alo);
      split8(&Wk[(size_t)oc * 128 + kk * 32 + lc * 8], &bhi, &blo);
      acc = __builtin_amdgcn_mfma_f32_16x16x32_bf16(ahi, bhi, acc, 0, 0, 0);
      acc = __builtin_amdgcn_mfma_f32_16x16x32_bf16(alo, bhi, acc, 0, 0, 0);
      acc = __builtin_amdgcn_mfma_f32_16x16x32_bf16(ahi, blo, acc, 0, 0, 0);
    }
    float bkv = bk[oc];
#pragma unroll
    for (int q = 0; q < 4; q++)
      kbf[(size_t)(r0 + 4 * lc + q) * 256 + oc] = f2bf(acc[q] + bkv);
  }
  // ---- V: k=128, store transposed [b][h][m] ----
  {
    f32x4 acc = {0.f, 0.f, 0.f, 0.f};
#pragma unroll
    for (int kk = 0; kk < 4; kk++) {
      s16x8 ahi, alo, bhi, blo;
      split8(&xa[lr * 132 + kk * 32 + lc * 8], &ahi, &alo);
      split8(&Wv[(size_t)oc * 128 + kk * 32 + lc * 8], &bhi, &blo);
      acc = __builtin_amdgcn_mfma_f32_16x16x32_bf16(ahi, bhi, acc, 0, 0, 0);
      acc = __builtin_amdgcn_mfma_f32_16x16x32_bf16(alo, bhi, acc, 0, 0, 0);
      acc = __builtin_amdgcn_mfma_f32_16x16x32_bf16(ahi, blo, acc, 0, 0, 0);
    }
    float bvv = bv[oc];
    int m0 = r0 & 127;
#pragma unroll
    for (int q = 0; q < 4; q++)
      vtbf[(size_t)(bb * 256 + oc) * 128 + m0 + 4 * lc + q] = f2bf(acc[q] + bvv);
  }
}

// 512 blocks x 512 threads (2 blocks/CU overlap). block = (b = bid&15, 4-row
// tile n0 = (bid>>4)*4). 16-row MFMA logits window (4x redundant - MFMA is
// ~free); softmax 1 (row,m)/thread; PV/O with zeroed non-owned A rows.
__global__ __launch_bounds__(512, 4) void attn_k(
    const float* __restrict__ goals, const float* __restrict__ agents_local,
    const float* __restrict__ u1, const float* __restrict__ u2,
    const float* __restrict__ bo, const float* __restrict__ Wsm,
    const float* __restrict__ bs, const float* __restrict__ ws,
    float* __restrict__ out) {
  const unsigned short* Qbf  = (const unsigned short*)(ws + QBF_OFF);
  const unsigned short* Kbf  = (const unsigned short*)(ws + KBF_OFF);
  const unsigned short* VTbf = (const unsigned short*)(ws + VTBF_OFF);
  const unsigned short* Wobf = (const unsigned short*)(ws + WOBF_OFF);
  float* o_logit = out + LOGIT_OFF;
  float* o_mask  = out + MASK_OFF;
  float* o_attn  = out + ATTN_OFF;
  float* o_out   = out + OUT_OFF;

  int bid = blockIdx.x;
  int b  = bid & 15;
  int n0 = (bid >> 4) << 2;    // 0..124 step 4
  int rtile = n0 & 0x70;       // 16-row MFMA window base
  int soff  = n0 & 12;         // our 4 rows within the window
  int t = threadIdx.x;
  int w = t >> 6, l = t & 63, lr = l & 15, lc = l >> 4;

  __shared__ __align__(16) float Sp[4][132];             // our 4 logit rows
  __shared__ __align__(16) unsigned short Wb[16 * 136];  // attn*mask (A of PV)
  __shared__ __align__(16) unsigned short Ib[16 * 264];  // info bf16 (A of O)
  __shared__ __align__(16) float outb[4 * 260];          // out rows (skill in)
  __shared__ float redmax[4][2], redsum[4][2];

  // ---- prefetch (hide HBM/L2 latency under phase L) ----
  int pm = t & 127, prl = t >> 7;
  int prow = b * 128 + n0 + prl;
  float uu1 = u1[(size_t)prow * 128 + pm];
  float uu2 = u2[(size_t)prow * 128 + pm];
  float bov0 = bo[w * 16 + lr];
  float bov1 = bo[(w + 8) * 16 + lr];

  // ---- phase L: logits MFMA. wave w -> m-tile w, k=256 (8 MFMAs) ----
  {
    const s16x8* ap = (const s16x8*)(Qbf + (size_t)(b * 128 + rtile + lr) * 256);
    const s16x8* bp = (const s16x8*)(Kbf + (size_t)(b * 128 + w * 16 + lr) * 256);
    f32x4 acc = {0.f, 0.f, 0.f, 0.f};
#pragma unroll
    for (int kk = 0; kk < 8; kk++)
      acc = __builtin_amdgcn_mfma_f32_16x16x32_bf16(ap[kk * 4 + lc], bp[kk * 4 + lc], acc, 0, 0, 0);
    if (lc == (soff >> 2)) {
#pragma unroll
      for (int q = 0; q < 4; q++) Sp[q][w * 16 + lr] = acc[q] * 0.0625f;
    }
    // zero ALL Wb rows (ours rewritten in phase S after the barrier)
    for (int i = t; i < 1088; i += 512) ((unsigned int*)Wb)[i] = 0u;
  }
  __syncthreads();

  // ---- phase S: gumbel-sigmoid mask + scores + softmax (1 pair/thread) ----
  {
    int half = (t >> 6) & 1;
    float lg = Sp[prl][pm];
    float g1 = -__logf(-__logf(uu1 + 1e-20f) + 1e-20f);
    float g2 = -__logf(-__logf(uu2 + 1e-20f) + 1e-20f);
    float z = lg + g1 - g2;                       // TAU = 1
    float mkv = 1.0f / (1.0f + __expf(-z));
    o_mask[(size_t)prow * 128 + pm] = mkv;
    float sc = lg + __logf(mkv + 1e-8f);
    float v = sc;
#pragma unroll
    for (int off = 32; off >= 1; off >>= 1) v = fmaxf(v, __shfl_xor(v, off));
    if (l == 0) redmax[prl][half] = v;
    __syncthreads();
    float rmax = fmaxf(redmax[prl][0], redmax[prl][1]);
    float e = __expf(sc - rmax);
    float s = e;
#pragma unroll
    for (int off = 32; off >= 1; off >>= 1) s += __shfl_xor(s, off);
    if (l == 0) redsum[prl][half] = s;
    __syncthreads();
    float rsum = redsum[prl][0] + redsum[prl][1];
    float attn = e / rsum;
    o_attn[(size_t)prow * 128 + pm] = attn;
    Wb[(soff + prl) * 136 + pm] = f2bf(attn * mkv);
  }
  __syncthreads();

  // ---- phase PV: info = W x V. wave w -> h-tiles w*16, (w+8)*16 ----
  {
#pragma unroll
    for (int hs = 0; hs < 2; hs++) {
      int h0 = (w + 8 * hs) * 16;
      f32x4 acc = {0.f, 0.f, 0.f, 0.f};
#pragma unroll
      for (int kk = 0; kk < 4; kk++) {
        s16x8 a = *(const s16x8*)(Wb + lr * 136 + kk * 32 + lc * 8);
        s16x8 bfr = *(const s16x8*)(VTbf + (size_t)(b * 256 + h0 + lr) * 128 + kk * 32 + lc * 8);
        acc = __builtin_amdgcn_mfma_f32_16x16x32_bf16(a, bfr, acc, 0, 0, 0);
      }
#pragma unroll
      for (int q = 0; q < 4; q++) Ib[(4 * lc + q) * 264 + h0 + lr] = f2bf(acc[q]);
    }
  }
  __syncthreads();

  // ---- phase O: out = info x Wo^T. wave w -> g-tiles w*16, (w+8)*16 ----
  {
#pragma unroll
    for (int gs = 0; gs < 2; gs++) {
      int g0 = (w + 8 * gs) * 16;
      f32x4 acc = {0.f, 0.f, 0.f, 0.f};
#pragma unroll
      for (int kk = 0; kk < 8; kk++) {
        s16x8 a = *(const s16x8*)(Ib + lr * 264 + kk * 32 + lc * 8);
        s16x8 bfr = *(const s16x8*)(Wobf + (size_t)(g0 + lr) * 256 + kk * 32 + lc * 8);
        acc = __builtin_amdgcn_mfma_f32_16x16x32_bf16(a, bfr, acc, 0, 0, 0);
      }
      float bov = gs ? bov1 : bov0;
      if (lc == (soff >> 2)) {                    // rows we own: q = 0..3
#pragma unroll
        for (int q = 0; q < 4; q++) {
          float val = acc[q] + bov;
          o_out[(size_t)(b * 128 + n0 + q) * 256 + g0 + lr] = val;
          outb[q * 260 + g0 + lr] = val;
        }
      }
    }
  }
  __syncthreads();

  // ---- phase K: skill logits. t = (rloc<<7)|(s<<3)|p, 8-way split-K ----
  {
    int rloc = t >> 7, s = (t >> 3) & 15, p = t & 7;
    int row = b * 128 + n0 + rloc;
    const float4* Ws4 = (const float4*)(Wsm + s * 384);
    const float4* lp4 = (const float4*)(agents_local + (size_t)row * 64);
    const float4* gp4 = (const float4*)(goals + (size_t)row * 64);
    float acc = 0.f;
#pragma unroll
    for (int i = 0; i < 12; i++) {
      int cc = p * 48 + i * 4;
      float4 c4;
      if (cc < 64)       c4 = lp4[cc >> 2];
      else if (cc < 128) c4 = gp4[(cc - 64) >> 2];
      else               c4 = *(const float4*)&outb[rloc * 260 + (cc - 128)];
      float4 w4 = Ws4[cc >> 2];
      acc = fmaf(w4.x, c4.x, fmaf(w4.y, c4.y, fmaf(w4.z, c4.z, fmaf(w4.w, c4.w, acc))));
    }
    acc += __shfl_xor(acc, 1);
    acc += __shfl_xor(acc, 2);
    acc += __shfl_xor(acc, 4);
    if (p == 0) o_logit[row * 16 + s] = acc + bs[s];
  }
}

extern "C" void kernel_launch(void* const* d_in, const int* in_sizes, int n_in,
                              void* d_out, int out_size, void* d_ws, size_t ws_size,
                              hipStream_t stream) {
  const float* goals        = (const float*)d_in[0];
  const float* agents       = (const float*)d_in[1];
  const float* agents_local = (const float*)d_in[2];
  const float* u1           = (const float*)d_in[3];
  const float* u2           = (const float*)d_in[4];
  const float* Wq = (const float*)d_in[5];
  const float* bq = (const float*)d_in[6];
  const float* Wk = (const float*)d_in[7];
  const float* bk = (const float*)d_in[8];
  const float* Wv = (const float*)d_in[9];
  const float* bv = (const float*)d_in[10];
  const float* Wo = (const float*)d_in[11];
  const float* bo = (const float*)d_in[12];
  const float* Wsm = (const float*)d_in[13];
  const float* bs  = (const float*)d_in[14];
  float* out = (float*)d_out;
  float* ws  = (float*)d_ws;

  proj_k<<<256, 512, 0, stream>>>(goals, agents, Wq, bq, Wk, bk, Wv, bv, Wo, ws);
  attn_k<<<512, 512, 0, stream>>>(goals, agents_local, u1, u2, bo, Wsm, bs, ws, out);
}